// Round 20
// baseline (136.327 us; speedup 1.0000x reference)
//
#include <hip/hip_runtime.h>
#include <cstdint>
#include <cstddef>

#define NPTS 2048
#define BATCH 8
#define CIN 64
#define CO 128
#define KNN 20
#define KSEL 24   // pool size per (query,csplit) written to POOLS
#define KSUB 16   // per-sub ladder (net output-error prob ~2e-8)
#define NSPLIT 4
#define KPAD 17   // padded mk row stride (words)

typedef short s16x8 __attribute__((ext_vector_type(8)));
typedef unsigned short u16x8 __attribute__((ext_vector_type(8)));
typedef float f32x4 __attribute__((ext_vector_type(4)));

__device__ inline unsigned short f2bf_rne(float x) {
  unsigned u = __float_as_uint(x);
  unsigned r = (u + 0x7FFFu + ((u >> 16) & 1u)) >> 16;
  return (unsigned short)r;
}
__device__ inline float bf2f(unsigned short h) {
  return __uint_as_float(((unsigned)h) << 16);
}
__device__ inline unsigned med3u(unsigned a, unsigned b, unsigned c) {
  unsigned d;
  asm("v_med3_u32 %0, %1, %2, %3" : "=v"(d) : "v"(a), "v"(b), "v"(c));
  return d;
}

// ---------------------------------------------------------------------------
// K1: prep (32-row half-tiles, grid 512). transpose x -> P; sq norms;
// split-bf16 fragment pack; block (0,0) zeroes STATS.
// ---------------------------------------------------------------------------
__global__ __launch_bounds__(256) void prep_kernel(
    const float* __restrict__ x, float* __restrict__ P,
    unsigned short* __restrict__ PG, float* __restrict__ SQ,
    float* __restrict__ STATS) {
  __shared__ float tile[64 * 33];
  const int b = blockIdx.y, hb = blockIdx.x;
  const int n0 = hb * 32;
  const int tid = threadIdx.x;
  if (b == 0 && hb == 0) {
    for (int t = tid; t < 5 * CO; t += 256) STATS[t] = 0.f;
  }
  const float* xb = x + (size_t)b * CIN * NPTS;
#pragma unroll
  for (int j = 0; j < 8; ++j) {
    int e = j * 256 + tid;
    int c = e >> 5, nl = e & 31;
    tile[c * 33 + nl] = xb[(size_t)c * NPTS + n0 + nl];
  }
  __syncthreads();
  float* Pb = P + (size_t)b * NPTS * CIN;
#pragma unroll
  for (int j = 0; j < 8; ++j) {
    int e = j * 256 + tid;
    int nl = e >> 6, c = e & 63;
    Pb[(size_t)(n0 + nl) * CIN + c] = tile[c * 33 + nl];
  }
  if (tid < 32) {
    float acc = 0.f;
#pragma unroll
    for (int c = 0; c < 64; ++c) {
      float v = tile[c * 33 + tid];
      acc = fmaf(v, v, acc);
    }
    SQ[(size_t)b * NPTS + n0 + tid] = acc;
  }
  const size_t tbase = (size_t)(b * 32 + (n0 >> 6)) * 8192;
  {
    const int rl = tid >> 3, kc = tid & 7;
    const int grow = (n0 & 63) + rl;
    const int frag = ((grow >> 4) << 1) | (kc >> 2);
    const int lidx = (grow & 15) | ((kc & 3) << 4);
    s16x8 hi8, lo8;
#pragma unroll
    for (int e = 0; e < 8; ++e) {
      float v = tile[(kc * 8 + e) * 33 + rl];
      unsigned short hb_ = f2bf_rne(v);
      float hf = bf2f(hb_);
      unsigned short lb = f2bf_rne(v - hf);
      hi8[e] = (short)hb_;
      lo8[e] = (short)lb;
    }
    size_t co = (size_t)(frag * 64 + lidx) * 8;
    *(s16x8*)(PG + tbase + co) = hi8;
    *(s16x8*)(PG + tbase + 4096 + co) = lo8;
  }
}

// ---------------------------------------------------------------------------
// K2a: partial KNN (round-19 proven: med3 ladder KSUB=16, unroll 2).
// ---------------------------------------------------------------------------
__global__ __launch_bounds__(256) void knn_part_kernel(
    const unsigned short* __restrict__ PG, const float* __restrict__ SQ,
    unsigned* __restrict__ POOLS) {
  const int b = blockIdx.z;
  const int cs = blockIdx.y;
  const int n0 = blockIdx.x * 64;
  const int tid = threadIdx.x;
  const int lane = tid & 63, w = tid >> 6;
  const int qi = w * 16 + (lane & 15);
  const int sub = lane >> 4;
  const int T0 = cs * 8;

  __shared__ unsigned mk[64 * 4 * KPAD];  // 17408 B

  const size_t tqb = (size_t)(b * 32 + (n0 >> 6)) * 8192;
  const s16x8 qhi0 = *(const s16x8*)(PG + tqb + (size_t)((w * 2 + 0) * 64 + lane) * 8);
  const s16x8 qhi1 = *(const s16x8*)(PG + tqb + (size_t)((w * 2 + 1) * 64 + lane) * 8);
  const s16x8 qlo0 = *(const s16x8*)(PG + tqb + 4096 + (size_t)((w * 2 + 0) * 64 + lane) * 8);
  const s16x8 qlo1 = *(const s16x8*)(PG + tqb + 4096 + (size_t)((w * 2 + 1) * 64 + lane) * 8);

  unsigned hk[KSUB];
#pragma unroll
  for (int s = 0; s < KSUB; ++s) hk[s] = 0xFFFFFFFFu;

#pragma unroll 2
  for (int t = 0; t < 8; ++t) {
    const int T = T0 + t;
    const unsigned short* tb = PG + (size_t)(b * 32 + T) * 8192;
#pragma unroll
    for (int rt = 0; rt < 4; ++rt) {
      const s16x8 ahi0 = *(const s16x8*)(tb + (size_t)((rt * 2 + 0) * 64 + lane) * 8);
      const s16x8 ahi1 = *(const s16x8*)(tb + (size_t)((rt * 2 + 1) * 64 + lane) * 8);
      const s16x8 alo0 = *(const s16x8*)(tb + 4096 + (size_t)((rt * 2 + 0) * 64 + lane) * 8);
      const s16x8 alo1 = *(const s16x8*)(tb + 4096 + (size_t)((rt * 2 + 1) * 64 + lane) * 8);
      f32x4 acc = {0.f, 0.f, 0.f, 0.f};
      acc = __builtin_amdgcn_mfma_f32_16x16x32_bf16(alo0, qhi0, acc, 0, 0, 0);
      acc = __builtin_amdgcn_mfma_f32_16x16x32_bf16(ahi0, qlo0, acc, 0, 0, 0);
      acc = __builtin_amdgcn_mfma_f32_16x16x32_bf16(ahi0, qhi0, acc, 0, 0, 0);
      acc = __builtin_amdgcn_mfma_f32_16x16x32_bf16(alo1, qhi1, acc, 0, 0, 0);
      acc = __builtin_amdgcn_mfma_f32_16x16x32_bf16(ahi1, qlo1, acc, 0, 0, 0);
      acc = __builtin_amdgcn_mfma_f32_16x16x32_bf16(ahi1, qhi1, acc, 0, 0, 0);
      const float4 sq4 = *(const float4*)(SQ + b * NPTS + T * 64 + rt * 16 + sub * 4);
      const float sqa[4] = {sq4.x, sq4.y, sq4.z, sq4.w};
      const int mbase = T * 64 + rt * 16 + sub * 4;
#pragma unroll
      for (int r = 0; r < 4; ++r) {
        float d = fmaf(acc[r], -2.0f, sqa[r]);
        unsigned u = __float_as_uint(d);
        unsigned ord = u ^ (unsigned)(((int)u >> 31) | 0x80000000);
        unsigned key = (ord & 0xFFFFF800u) | (unsigned)(mbase + r);
#pragma unroll
        for (int s = KSUB - 1; s >= 1; --s) hk[s] = med3u(hk[s - 1], hk[s], key);
        hk[0] = hk[0] < key ? hk[0] : key;
      }
    }
  }

#pragma unroll
  for (int s = 0; s < KSUB; ++s) mk[(qi * 4 + sub) * KPAD + s] = hk[s];
  __syncthreads();

  if (sub == 0) {
    const unsigned* bl = mk + qi * 4 * KPAD;
    unsigned* pq = POOLS + ((size_t)(b * NPTS + n0 + qi) * NSPLIT + cs) * KSEL;
    int p0 = 0, p1 = 0, p2 = 0, p3 = 0;
#pragma unroll 1
    for (int s = 0; s < KSEL; ++s) {
      unsigned k0 = (p0 < KSUB) ? bl[0 * KPAD + p0] : 0xFFFFFFFFu;
      unsigned k1 = (p1 < KSUB) ? bl[1 * KPAD + p1] : 0xFFFFFFFFu;
      unsigned k2 = (p2 < KSUB) ? bl[2 * KPAD + p2] : 0xFFFFFFFFu;
      unsigned k3 = (p3 < KSUB) ? bl[3 * KPAD + p3] : 0xFFFFFFFFu;
      unsigned bk = k0; int bs = 0;
      if (k1 < bk) { bk = k1; bs = 1; }
      if (k2 < bk) { bk = k2; bs = 2; }
      if (k3 < bk) { bk = k3; bs = 3; }
      pq[s] = bk;
      if (bs == 0) ++p0; else if (bs == 1) ++p1; else if (bs == 2) ++p2; else ++p3;
    }
  }
}

// ---------------------------------------------------------------------------
// K2b+K3 fused: blocks [0,512) = proj (128 rows x 32 outs, 2 rows/thread:
// halves LDS reads per FMA); blocks [512,1024) = merge (parallel 4-way
// rank-merge phase A, round-5-proven).
// ---------------------------------------------------------------------------
__global__ __launch_bounds__(256) void merge_proj_kernel(
    const float* __restrict__ P, const float* __restrict__ W,
    const unsigned* __restrict__ POOLS, int* __restrict__ IDX,
    unsigned short* __restrict__ Uh, unsigned short* __restrict__ Vh) {
  __shared__ __align__(16) char smem[51712];  // proj: Pt 33280 + W 2*9216
  const int tid = threadIdx.x;

  if (blockIdx.x < 512) {
    // ---------------- proj path ----------------
    const int blk = blockIdx.x;
    const int r0 = (blk >> 2) * 128;
    const int o0 = (blk & 3) * 32;
    const int og = tid & 3;
    const int rg = tid >> 2;            // 0..63 -> rows rg*2, rg*2+1
    float* Pt = (float*)smem;           // [128][65]
    float* Wu_s = Pt + 128 * 65;        // [64][36]
    float* Wd_s = Wu_s + 64 * 36;

#pragma unroll
    for (int j = 0; j < 32; ++j) {
      int e = j * 256 + tid;
      int c = e & 63, rl = e >> 6;
      Pt[rl * 65 + c] = P[((size_t)(r0 + rl) << 6) + c];
    }
#pragma unroll
    for (int j = 0; j < 8; ++j) {
      int e = j * 256 + tid;
      int c = e & 63, ol = e >> 6;
      float w1 = W[(size_t)(o0 + ol) * 128 + c];
      float w2 = W[(size_t)(o0 + ol) * 128 + 64 + c];
      Wu_s[c * 36 + ol] = w1 - w2;
      Wd_s[c * 36 + ol] = w2;
    }
    __syncthreads();

    float au0[8] = {0,0,0,0,0,0,0,0}, au1[8] = {0,0,0,0,0,0,0,0};
    float av0[8] = {0,0,0,0,0,0,0,0}, av1[8] = {0,0,0,0,0,0,0,0};
#pragma unroll 4
    for (int c = 0; c < 64; ++c) {
      float pa = Pt[(rg * 2 + 0) * 65 + c];
      float pb = Pt[(rg * 2 + 1) * 65 + c];
      const float* wu = Wu_s + c * 36 + og * 8;
      const float* wd = Wd_s + c * 36 + og * 8;
      float4 u0 = *(const float4*)wu;
      float4 u1 = *(const float4*)(wu + 4);
      float4 dd0 = *(const float4*)wd;
      float4 dd1 = *(const float4*)(wd + 4);
      au0[0] = fmaf(pa, u0.x, au0[0]); au0[1] = fmaf(pa, u0.y, au0[1]);
      au0[2] = fmaf(pa, u0.z, au0[2]); au0[3] = fmaf(pa, u0.w, au0[3]);
      au0[4] = fmaf(pa, u1.x, au0[4]); au0[5] = fmaf(pa, u1.y, au0[5]);
      au0[6] = fmaf(pa, u1.z, au0[6]); au0[7] = fmaf(pa, u1.w, au0[7]);
      av0[0] = fmaf(pa, dd0.x, av0[0]); av0[1] = fmaf(pa, dd0.y, av0[1]);
      av0[2] = fmaf(pa, dd0.z, av0[2]); av0[3] = fmaf(pa, dd0.w, av0[3]);
      av0[4] = fmaf(pa, dd1.x, av0[4]); av0[5] = fmaf(pa, dd1.y, av0[5]);
      av0[6] = fmaf(pa, dd1.z, av0[6]); av0[7] = fmaf(pa, dd1.w, av0[7]);
      au1[0] = fmaf(pb, u0.x, au1[0]); au1[1] = fmaf(pb, u0.y, au1[1]);
      au1[2] = fmaf(pb, u0.z, au1[2]); au1[3] = fmaf(pb, u0.w, au1[3]);
      au1[4] = fmaf(pb, u1.x, au1[4]); au1[5] = fmaf(pb, u1.y, au1[5]);
      au1[6] = fmaf(pb, u1.z, au1[6]); au1[7] = fmaf(pb, u1.w, au1[7]);
      av1[0] = fmaf(pb, dd0.x, av1[0]); av1[1] = fmaf(pb, dd0.y, av1[1]);
      av1[2] = fmaf(pb, dd0.z, av1[2]); av1[3] = fmaf(pb, dd0.w, av1[3]);
      av1[4] = fmaf(pb, dd1.x, av1[4]); av1[5] = fmaf(pb, dd1.y, av1[5]);
      av1[6] = fmaf(pb, dd1.z, av1[6]); av1[7] = fmaf(pb, dd1.w, av1[7]);
    }
    size_t ob0 = (size_t)(r0 + rg * 2 + 0) * CO + o0 + og * 8;
    size_t ob1 = (size_t)(r0 + rg * 2 + 1) * CO + o0 + og * 8;
    u16x8 hu0, hv0, hu1, hv1;
#pragma unroll
    for (int j = 0; j < 8; ++j) {
      hu0[j] = f2bf_rne(au0[j]); hv0[j] = f2bf_rne(av0[j]);
      hu1[j] = f2bf_rne(au1[j]); hv1[j] = f2bf_rne(av1[j]);
    }
    *(u16x8*)(Uh + ob0) = hu0;
    *(u16x8*)(Vh + ob0) = hv0;
    *(u16x8*)(Uh + ob1) = hu1;
    *(u16x8*)(Vh + ob1) = hv1;
  } else {
    // ---------------- merge path ----------------
    const int mblk = blockIdx.x - 512;
    const int qi = tid >> 3, st = tid & 7;
    const int r0 = mblk * 32;
    const int r = r0 + qi;
    const int b = r >> 11;

    unsigned* lists = (unsigned*)smem;              // 32*4*24 words
    unsigned* pool = lists + 32 * NSPLIT * KSEL;    // 32*24 words
    double* cd = (double*)(pool + 32 * KSEL);       // 32*24 f64

    {
      const unsigned* src = POOLS + (size_t)r0 * NSPLIT * KSEL;
      for (int t = tid; t < 32 * NSPLIT * KSEL; t += 256) lists[t] = src[t];
    }
    __syncthreads();

    // Phase A: parallel rank merge (st<4): my list vs the other three.
    if (st < 4) {
      const unsigned* Lm = lists + (qi * NSPLIT + st) * KSEL;
      const unsigned* L0 = lists + (qi * NSPLIT + ((st + 1) & 3)) * KSEL;
      const unsigned* L1 = lists + (qi * NSPLIT + ((st + 2) & 3)) * KSEL;
      const unsigned* L2 = lists + (qi * NSPLIT + ((st + 3) & 3)) * KSEL;
      int p0 = 0, p1 = 0, p2 = 0;
#pragma unroll 1
      for (int i = 0; i < KSEL; ++i) {
        unsigned key = Lm[i];
        while (p0 < KSEL && L0[p0] < key) ++p0;
        while (p1 < KSEL && L1[p1] < key) ++p1;
        while (p2 < KSEL && L2[p2] < key) ++p2;
        int rank = i + p0 + p1 + p2;
        if (rank >= KSEL) break;  // monotone in i
        pool[qi * KSEL + rank] = key;
      }
    }
    __syncthreads();

    const float* qrow = P + ((size_t)r << 6);
    float4 q4[16];
#pragma unroll
    for (int t = 0; t < 16; ++t) q4[t] = ((const float4*)qrow)[t];
#pragma unroll 1
    for (int j = 0; j < 3; ++j) {
      int cand = st * 3 + j;
      unsigned key = pool[qi * KSEL + cand];
      int m = (int)(key & 0x7FFu);
      const float* prow = P + ((size_t)(b * NPTS + m) << 6);
      double a0 = 0.0, a1 = 0.0;
#pragma unroll
      for (int t = 0; t < 16; ++t) {
        float4 pv = ((const float4*)prow)[t];
        double d0 = (double)pv.x - (double)q4[t].x;
        double d1 = (double)pv.y - (double)q4[t].y;
        double d2 = (double)pv.z - (double)q4[t].z;
        double d3 = (double)pv.w - (double)q4[t].w;
        a0 = fma(d1, d1, fma(d0, d0, a0));
        a1 = fma(d3, d3, fma(d2, d2, a1));
      }
      cd[qi * KSEL + cand] = a0 + a1;
    }
    __syncthreads();

    int* op = IDX + (size_t)r * KNN;
#pragma unroll 1
    for (int j = 0; j < 3; ++j) {
      int cand = st * 3 + j;
      double dv = cd[qi * KSEL + cand];
      int iv = (int)(pool[qi * KSEL + cand] & 0x7FFu);
      int rk = 0;
#pragma unroll 1
      for (int t = 0; t < KSEL; ++t) {
        double dt = cd[qi * KSEL + t];
        int it = (int)(pool[qi * KSEL + t] & 0x7FFu);
        rk += ((dt < dv) || (dt == dv && it < iv)) ? 1 : 0;
      }
      if (rk < KNN) op[rk] = iv;
    }
  }
}

// ---------------------------------------------------------------------------
// K4: fused gather (bf16 U,V) + maxpool + BN-stat partials. Z stored bf16.
// ---------------------------------------------------------------------------
__global__ __launch_bounds__(256) void gstats_kernel(
    const unsigned short* __restrict__ Uh, const unsigned short* __restrict__ Vh,
    const int* __restrict__ IDX, unsigned short* __restrict__ Zh,
    float* __restrict__ STATS) {
  const int r0 = blockIdx.x * 16;
  const int tid = threadIdx.x;
  const int og = tid & 15, nl = tid >> 4;
  const int r = r0 + nl;
  const int b = r >> 11;
  const unsigned short* Vb = Vh + ((size_t)b << 11) * CO;

  __shared__ int ii[16 * KNN];
  __shared__ float red[4][5][128];

  for (int t = tid; t < 16 * KNN; t += 256) ii[t] = IDX[(size_t)r0 * KNN + t];
  __syncthreads();

  float vmax[8], svr[8], svvr[8];
#pragma unroll
  for (int j = 0; j < 8; ++j) { vmax[j] = -3.4e38f; svr[j] = 0.f; svvr[j] = 0.f; }
#pragma unroll 4
  for (int k = 0; k < KNN; ++k) {
    int idx = ii[nl * KNN + k];
    u16x8 hv = *(const u16x8*)(Vb + (size_t)idx * CO + og * 8);
#pragma unroll
    for (int j = 0; j < 8; ++j) {
      float v = bf2f((unsigned short)hv[j]);
      vmax[j] = fmaxf(vmax[j], v);
      svr[j] += v;
      svvr[j] = fmaf(v, v, svvr[j]);
    }
  }
  size_t ob = (size_t)r * CO + og * 8;
  u16x8 hu = *(const u16x8*)(Uh + ob);
  float uu[8];
#pragma unroll
  for (int j = 0; j < 8; ++j) uu[j] = bf2f((unsigned short)hu[j]);
  u16x8 zh;
#pragma unroll
  for (int j = 0; j < 8; ++j) zh[j] = f2bf_rne(uu[j] + vmax[j]);
  *(u16x8*)(Zh + ob) = zh;

  float pu[8], puu[8], psv[8], pusv[8], psvv[8];
#pragma unroll
  for (int j = 0; j < 8; ++j) {
    pu[j] = uu[j];
    puu[j] = uu[j] * uu[j];
    psv[j] = svr[j];
    pusv[j] = uu[j] * svr[j];
    psvv[j] = svvr[j];
  }
#pragma unroll
  for (int j = 0; j < 8; ++j) {
    pu[j]   += __shfl_xor(pu[j], 16);   pu[j]   += __shfl_xor(pu[j], 32);
    puu[j]  += __shfl_xor(puu[j], 16);  puu[j]  += __shfl_xor(puu[j], 32);
    psv[j]  += __shfl_xor(psv[j], 16);  psv[j]  += __shfl_xor(psv[j], 32);
    pusv[j] += __shfl_xor(pusv[j], 16); pusv[j] += __shfl_xor(pusv[j], 32);
    psvv[j] += __shfl_xor(psvv[j], 16); psvv[j] += __shfl_xor(psvv[j], 32);
  }
  const int w = tid >> 6;
  if ((tid & 0x30) == 0) {
#pragma unroll
    for (int j = 0; j < 8; ++j) {
      int c = og * 8 + j;
      red[w][0][c] = pu[j];  red[w][1][c] = puu[j];  red[w][2][c] = psv[j];
      red[w][3][c] = pusv[j]; red[w][4][c] = psvv[j];
    }
  }
  __syncthreads();
  if (tid < 128) {
#pragma unroll
    for (int s = 0; s < 5; ++s) {
      float v4 = red[0][s][tid] + red[1][s][tid] + red[2][s][tid] + red[3][s][tid];
      atomicAdd(&STATS[s * CO + tid], v4);
    }
  }
}

// ---------------------------------------------------------------------------
// K5: affine + ReLU + transpose write (bf16 Z in), per-block BN finalize.
// ---------------------------------------------------------------------------
__global__ __launch_bounds__(256) void out_kernel(
    const unsigned short* __restrict__ Zh, const float* __restrict__ STATS,
    const float* __restrict__ bias, const float* __restrict__ gamma,
    const float* __restrict__ beta, float* __restrict__ out) {
  const int n0 = blockIdx.x * 64, o0 = blockIdx.y * 32, b = blockIdx.z;
  const int tid = threadIdx.x;
  __shared__ float tile[64 * 33];
  __shared__ float fs[32], ft[32];
  if (tid < 32) {
    const int o = o0 + tid;
    const float M = (float)(BATCH * NPTS * KNN);
    const float Kf = (float)KNN;
    float su = STATS[0 * CO + o], suu = STATS[1 * CO + o], ssv = STATS[2 * CO + o];
    float susv = STATS[3 * CO + o], ssvv = STATS[4 * CO + o];
    float bo = bias[o];
    float lin = (Kf * su + ssv) / M;
    float mean = lin + bo;
    float ey2 = (Kf * suu + ssvv + 2.0f * susv) / M + 2.0f * bo * lin + bo * bo;
    float var = ey2 - mean * mean;
    float scale = gamma[o] * rsqrtf(var + 1e-5f);
    fs[tid] = scale;
    ft[tid] = (bo - mean) * scale + beta[o];
  }
#pragma unroll
  for (int j = 0; j < 8; ++j) {
    int e = j * 256 + tid;
    int ol = e & 31, nl = e >> 5;
    tile[nl * 33 + ol] = bf2f(Zh[(size_t)(b * NPTS + n0 + nl) * CO + o0 + ol]);
  }
  __syncthreads();
#pragma unroll
  for (int j = 0; j < 8; ++j) {
    int e = j * 256 + tid;
    int nl = e & 63, ol = e >> 6;
    float v = fmaf(tile[nl * 33 + ol], fs[ol], ft[ol]);
    out[(size_t)(b * CO + o0 + ol) * NPTS + n0 + nl] = fmaxf(v, 0.0f);
  }
}

// ---------------------------------------------------------------------------
extern "C" void kernel_launch(void* const* d_in, const int* in_sizes, int n_in,
                              void* d_out, int out_size, void* d_ws, size_t ws_size,
                              hipStream_t stream) {
  const float* x = (const float*)d_in[0];
  const float* W = (const float*)d_in[1];
  const float* bias = (const float*)d_in[2];
  const float* gamma = (const float*)d_in[3];
  const float* beta = (const float*)d_in[4];
  float* out = (float*)d_out;
  float* ws = (float*)d_ws;

  const size_t NR = (size_t)BATCH * NPTS;  // 16384
  size_t off = 0;
  float* P = ws + off;                      off += NR * CIN;
  unsigned short* PG = (unsigned short*)(ws + off); off += NR * CIN;
  float* SQ = ws + off;                     off += NR;
  int* IDX = (int*)(ws + off);              off += NR * KNN;
  unsigned short* Uh = (unsigned short*)(ws + off); off += NR * CO / 2;
  unsigned short* Vh = (unsigned short*)(ws + off); off += NR * CO / 2;
  unsigned* POOLS = (unsigned*)(ws + off);  off += NR * NSPLIT * KSEL;
  float* STATS = ws + off;                  off += 5 * CO;
  // Zh (bf16, 4 MB) aliases P (dead after merge_proj).
  unsigned short* Zh = (unsigned short*)ws;
  if (ws_size < off * sizeof(float)) return;

  prep_kernel<<<dim3(NPTS / 32, BATCH), 256, 0, stream>>>(x, P, PG, SQ, STATS);
  knn_part_kernel<<<dim3(NPTS / 64, NSPLIT, BATCH), 256, 0, stream>>>(PG, SQ, POOLS);
  merge_proj_kernel<<<dim3(512 + NR / 32), 256, 0, stream>>>(P, W, POOLS, IDX, Uh, Vh);
  gstats_kernel<<<dim3(NR / 16), 256, 0, stream>>>(Uh, Vh, IDX, Zh, STATS);
  out_kernel<<<dim3(NPTS / 64, CO / 32, BATCH), 256, 0, stream>>>(Zh, STATS, bias, gamma, beta, out);
}

// Round 21
// 121.716 us; speedup vs baseline: 1.1200x; 1.1200x over previous
//
#include <hip/hip_runtime.h>
#include <cstdint>
#include <cstddef>

#define NPTS 2048
#define BATCH 8
#define CIN 64
#define CO 128
#define KNN 20
#define KSEL 24   // pool size per (query,csplit) written to POOLS
#define KSUB 16   // per-sub ladder (net output-error prob ~2e-8)
#define NSPLIT 4
#define KPAD 17   // padded mk row stride (words)

typedef short s16x8 __attribute__((ext_vector_type(8)));
typedef unsigned short u16x8 __attribute__((ext_vector_type(8)));
typedef float f32x4 __attribute__((ext_vector_type(4)));

__device__ inline unsigned short f2bf_rne(float x) {
  unsigned u = __float_as_uint(x);
  unsigned r = (u + 0x7FFFu + ((u >> 16) & 1u)) >> 16;
  return (unsigned short)r;
}
__device__ inline float bf2f(unsigned short h) {
  return __uint_as_float(((unsigned)h) << 16);
}
__device__ inline unsigned med3u(unsigned a, unsigned b, unsigned c) {
  unsigned d;
  asm("v_med3_u32 %0, %1, %2, %3" : "=v"(d) : "v"(a), "v"(b), "v"(c));
  return d;
}

// ---------------------------------------------------------------------------
// K1: prep (32-row half-tiles, grid 512). transpose x -> P; sq norms;
// split-bf16 fragment pack; block (0,0) zeroes STATS.
// ---------------------------------------------------------------------------
__global__ __launch_bounds__(256) void prep_kernel(
    const float* __restrict__ x, float* __restrict__ P,
    unsigned short* __restrict__ PG, float* __restrict__ SQ,
    float* __restrict__ STATS) {
  __shared__ float tile[64 * 33];
  const int b = blockIdx.y, hb = blockIdx.x;
  const int n0 = hb * 32;
  const int tid = threadIdx.x;
  if (b == 0 && hb == 0) {
    for (int t = tid; t < 5 * CO; t += 256) STATS[t] = 0.f;
  }
  const float* xb = x + (size_t)b * CIN * NPTS;
#pragma unroll
  for (int j = 0; j < 8; ++j) {
    int e = j * 256 + tid;
    int c = e >> 5, nl = e & 31;
    tile[c * 33 + nl] = xb[(size_t)c * NPTS + n0 + nl];
  }
  __syncthreads();
  float* Pb = P + (size_t)b * NPTS * CIN;
#pragma unroll
  for (int j = 0; j < 8; ++j) {
    int e = j * 256 + tid;
    int nl = e >> 6, c = e & 63;
    Pb[(size_t)(n0 + nl) * CIN + c] = tile[c * 33 + nl];
  }
  if (tid < 32) {
    float acc = 0.f;
#pragma unroll
    for (int c = 0; c < 64; ++c) {
      float v = tile[c * 33 + tid];
      acc = fmaf(v, v, acc);
    }
    SQ[(size_t)b * NPTS + n0 + tid] = acc;
  }
  const size_t tbase = (size_t)(b * 32 + (n0 >> 6)) * 8192;
  {
    const int rl = tid >> 3, kc = tid & 7;
    const int grow = (n0 & 63) + rl;
    const int frag = ((grow >> 4) << 1) | (kc >> 2);
    const int lidx = (grow & 15) | ((kc & 3) << 4);
    s16x8 hi8, lo8;
#pragma unroll
    for (int e = 0; e < 8; ++e) {
      float v = tile[(kc * 8 + e) * 33 + rl];
      unsigned short hb_ = f2bf_rne(v);
      float hf = bf2f(hb_);
      unsigned short lb = f2bf_rne(v - hf);
      hi8[e] = (short)hb_;
      lo8[e] = (short)lb;
    }
    size_t co = (size_t)(frag * 64 + lidx) * 8;
    *(s16x8*)(PG + tbase + co) = hi8;
    *(s16x8*)(PG + tbase + 4096 + co) = lo8;
  }
}

// ---------------------------------------------------------------------------
// K2a: partial KNN (round-19 proven: med3 ladder KSUB=16, unroll 2).
// ---------------------------------------------------------------------------
__global__ __launch_bounds__(256) void knn_part_kernel(
    const unsigned short* __restrict__ PG, const float* __restrict__ SQ,
    unsigned* __restrict__ POOLS) {
  const int b = blockIdx.z;
  const int cs = blockIdx.y;
  const int n0 = blockIdx.x * 64;
  const int tid = threadIdx.x;
  const int lane = tid & 63, w = tid >> 6;
  const int qi = w * 16 + (lane & 15);
  const int sub = lane >> 4;
  const int T0 = cs * 8;

  __shared__ unsigned mk[64 * 4 * KPAD];  // 17408 B

  const size_t tqb = (size_t)(b * 32 + (n0 >> 6)) * 8192;
  const s16x8 qhi0 = *(const s16x8*)(PG + tqb + (size_t)((w * 2 + 0) * 64 + lane) * 8);
  const s16x8 qhi1 = *(const s16x8*)(PG + tqb + (size_t)((w * 2 + 1) * 64 + lane) * 8);
  const s16x8 qlo0 = *(const s16x8*)(PG + tqb + 4096 + (size_t)((w * 2 + 0) * 64 + lane) * 8);
  const s16x8 qlo1 = *(const s16x8*)(PG + tqb + 4096 + (size_t)((w * 2 + 1) * 64 + lane) * 8);

  unsigned hk[KSUB];
#pragma unroll
  for (int s = 0; s < KSUB; ++s) hk[s] = 0xFFFFFFFFu;

#pragma unroll 2
  for (int t = 0; t < 8; ++t) {
    const int T = T0 + t;
    const unsigned short* tb = PG + (size_t)(b * 32 + T) * 8192;
#pragma unroll
    for (int rt = 0; rt < 4; ++rt) {
      const s16x8 ahi0 = *(const s16x8*)(tb + (size_t)((rt * 2 + 0) * 64 + lane) * 8);
      const s16x8 ahi1 = *(const s16x8*)(tb + (size_t)((rt * 2 + 1) * 64 + lane) * 8);
      const s16x8 alo0 = *(const s16x8*)(tb + 4096 + (size_t)((rt * 2 + 0) * 64 + lane) * 8);
      const s16x8 alo1 = *(const s16x8*)(tb + 4096 + (size_t)((rt * 2 + 1) * 64 + lane) * 8);
      f32x4 acc = {0.f, 0.f, 0.f, 0.f};
      acc = __builtin_amdgcn_mfma_f32_16x16x32_bf16(alo0, qhi0, acc, 0, 0, 0);
      acc = __builtin_amdgcn_mfma_f32_16x16x32_bf16(ahi0, qlo0, acc, 0, 0, 0);
      acc = __builtin_amdgcn_mfma_f32_16x16x32_bf16(ahi0, qhi0, acc, 0, 0, 0);
      acc = __builtin_amdgcn_mfma_f32_16x16x32_bf16(alo1, qhi1, acc, 0, 0, 0);
      acc = __builtin_amdgcn_mfma_f32_16x16x32_bf16(ahi1, qlo1, acc, 0, 0, 0);
      acc = __builtin_amdgcn_mfma_f32_16x16x32_bf16(ahi1, qhi1, acc, 0, 0, 0);
      const float4 sq4 = *(const float4*)(SQ + b * NPTS + T * 64 + rt * 16 + sub * 4);
      const float sqa[4] = {sq4.x, sq4.y, sq4.z, sq4.w};
      const int mbase = T * 64 + rt * 16 + sub * 4;
#pragma unroll
      for (int r = 0; r < 4; ++r) {
        float d = fmaf(acc[r], -2.0f, sqa[r]);
        unsigned u = __float_as_uint(d);
        unsigned ord = u ^ (unsigned)(((int)u >> 31) | 0x80000000);
        unsigned key = (ord & 0xFFFFF800u) | (unsigned)(mbase + r);
#pragma unroll
        for (int s = KSUB - 1; s >= 1; --s) hk[s] = med3u(hk[s - 1], hk[s], key);
        hk[0] = hk[0] < key ? hk[0] : key;
      }
    }
  }

#pragma unroll
  for (int s = 0; s < KSUB; ++s) mk[(qi * 4 + sub) * KPAD + s] = hk[s];
  __syncthreads();

  if (sub == 0) {
    const unsigned* bl = mk + qi * 4 * KPAD;
    unsigned* pq = POOLS + ((size_t)(b * NPTS + n0 + qi) * NSPLIT + cs) * KSEL;
    int p0 = 0, p1 = 0, p2 = 0, p3 = 0;
#pragma unroll 1
    for (int s = 0; s < KSEL; ++s) {
      unsigned k0 = (p0 < KSUB) ? bl[0 * KPAD + p0] : 0xFFFFFFFFu;
      unsigned k1 = (p1 < KSUB) ? bl[1 * KPAD + p1] : 0xFFFFFFFFu;
      unsigned k2 = (p2 < KSUB) ? bl[2 * KPAD + p2] : 0xFFFFFFFFu;
      unsigned k3 = (p3 < KSUB) ? bl[3 * KPAD + p3] : 0xFFFFFFFFu;
      unsigned bk = k0; int bs = 0;
      if (k1 < bk) { bk = k1; bs = 1; }
      if (k2 < bk) { bk = k2; bs = 2; }
      if (k3 < bk) { bk = k3; bs = 3; }
      pq[s] = bk;
      if (bs == 0) ++p0; else if (bs == 1) ++p1; else if (bs == 2) ++p2; else ++p3;
    }
  }
}

// ---------------------------------------------------------------------------
// K2b+K3 fused: blocks [0,512) = proj (128 rows x 32 outs, 2 rows/thread,
// Pt stored bf16 c-major so both rows load as ONE b32 and LDS stays 35 KB);
// blocks [512,1024) = merge (round-19 exact serial phase A).
// ---------------------------------------------------------------------------
__global__ __launch_bounds__(256) void merge_proj_kernel(
    const float* __restrict__ P, const float* __restrict__ W,
    const unsigned* __restrict__ POOLS, int* __restrict__ IDX,
    unsigned short* __restrict__ Uh, unsigned short* __restrict__ Vh) {
  __shared__ __align__(16) char smem[35072];
  const int tid = threadIdx.x;

  if (blockIdx.x < 512) {
    // ---------------- proj path ----------------
    const int blk = blockIdx.x;
    const int r0 = (blk >> 2) * 128;
    const int o0 = (blk & 3) * 32;
    const int og = tid & 3;
    const int rg = tid >> 2;                 // 0..63 -> rows rg*2, rg*2+1
    unsigned short* Pt = (unsigned short*)smem;      // [64 c][130 rows] bf16
    float* Wu_s = (float*)(smem + 64 * 130 * 2);     // [64][36]
    float* Wd_s = Wu_s + 64 * 36;                    // [64][36]

    // stage P tile as bf16, c-major (coalesced global reads)
#pragma unroll
    for (int j = 0; j < 32; ++j) {
      int e = j * 256 + tid;
      int c = e & 63, row = e >> 6;
      Pt[c * 130 + row] = f2bf_rne(P[((size_t)(r0 + row) << 6) + c]);
    }
#pragma unroll
    for (int j = 0; j < 8; ++j) {
      int e = j * 256 + tid;
      int c = e & 63, ol = e >> 6;
      float w1 = W[(size_t)(o0 + ol) * 128 + c];
      float w2 = W[(size_t)(o0 + ol) * 128 + 64 + c];
      Wu_s[c * 36 + ol] = w1 - w2;
      Wd_s[c * 36 + ol] = w2;
    }
    __syncthreads();

    float au0[8] = {0,0,0,0,0,0,0,0}, au1[8] = {0,0,0,0,0,0,0,0};
    float av0[8] = {0,0,0,0,0,0,0,0}, av1[8] = {0,0,0,0,0,0,0,0};
#pragma unroll 4
    for (int c = 0; c < 64; ++c) {
      unsigned pv = *(const unsigned*)(Pt + c * 130 + rg * 2);
      float pa = bf2f((unsigned short)(pv & 0xFFFFu));
      float pb = bf2f((unsigned short)(pv >> 16));
      const float* wu = Wu_s + c * 36 + og * 8;
      const float* wd = Wd_s + c * 36 + og * 8;
      float4 u0 = *(const float4*)wu;
      float4 u1 = *(const float4*)(wu + 4);
      float4 dd0 = *(const float4*)wd;
      float4 dd1 = *(const float4*)(wd + 4);
      au0[0] = fmaf(pa, u0.x, au0[0]); au0[1] = fmaf(pa, u0.y, au0[1]);
      au0[2] = fmaf(pa, u0.z, au0[2]); au0[3] = fmaf(pa, u0.w, au0[3]);
      au0[4] = fmaf(pa, u1.x, au0[4]); au0[5] = fmaf(pa, u1.y, au0[5]);
      au0[6] = fmaf(pa, u1.z, au0[6]); au0[7] = fmaf(pa, u1.w, au0[7]);
      av0[0] = fmaf(pa, dd0.x, av0[0]); av0[1] = fmaf(pa, dd0.y, av0[1]);
      av0[2] = fmaf(pa, dd0.z, av0[2]); av0[3] = fmaf(pa, dd0.w, av0[3]);
      av0[4] = fmaf(pa, dd1.x, av0[4]); av0[5] = fmaf(pa, dd1.y, av0[5]);
      av0[6] = fmaf(pa, dd1.z, av0[6]); av0[7] = fmaf(pa, dd1.w, av0[7]);
      au1[0] = fmaf(pb, u0.x, au1[0]); au1[1] = fmaf(pb, u0.y, au1[1]);
      au1[2] = fmaf(pb, u0.z, au1[2]); au1[3] = fmaf(pb, u0.w, au1[3]);
      au1[4] = fmaf(pb, u1.x, au1[4]); au1[5] = fmaf(pb, u1.y, au1[5]);
      au1[6] = fmaf(pb, u1.z, au1[6]); au1[7] = fmaf(pb, u1.w, au1[7]);
      av1[0] = fmaf(pb, dd0.x, av1[0]); av1[1] = fmaf(pb, dd0.y, av1[1]);
      av1[2] = fmaf(pb, dd0.z, av1[2]); av1[3] = fmaf(pb, dd0.w, av1[3]);
      av1[4] = fmaf(pb, dd1.x, av1[4]); av1[5] = fmaf(pb, dd1.y, av1[5]);
      av1[6] = fmaf(pb, dd1.z, av1[6]); av1[7] = fmaf(pb, dd1.w, av1[7]);
    }
    size_t ob0 = (size_t)(r0 + rg * 2 + 0) * CO + o0 + og * 8;
    size_t ob1 = (size_t)(r0 + rg * 2 + 1) * CO + o0 + og * 8;
    u16x8 hu0, hv0, hu1, hv1;
#pragma unroll
    for (int j = 0; j < 8; ++j) {
      hu0[j] = f2bf_rne(au0[j]); hv0[j] = f2bf_rne(av0[j]);
      hu1[j] = f2bf_rne(au1[j]); hv1[j] = f2bf_rne(av1[j]);
    }
    *(u16x8*)(Uh + ob0) = hu0;
    *(u16x8*)(Vh + ob0) = hv0;
    *(u16x8*)(Uh + ob1) = hu1;
    *(u16x8*)(Vh + ob1) = hv1;
  } else {
    // ---------------- merge path (round-19 exact) ----------------
    const int mblk = blockIdx.x - 512;
    const int qi = tid >> 3, st = tid & 7;
    const int r0 = mblk * 32;
    const int r = r0 + qi;
    const int b = r >> 11;

    unsigned* lists = (unsigned*)smem;
    unsigned* pool = lists + 32 * NSPLIT * KSEL;
    double* cd = (double*)(pool + 32 * KSEL);

    {
      const unsigned* src = POOLS + (size_t)r0 * NSPLIT * KSEL;
      for (int t = tid; t < 32 * NSPLIT * KSEL; t += 256) lists[t] = src[t];
    }
    __syncthreads();

    if (st == 0) {
      const unsigned* bl = lists + qi * NSPLIT * KSEL;
      unsigned* pq = pool + qi * KSEL;
      int p0 = 0, p1 = 0, p2 = 0, p3 = 0;
#pragma unroll 1
      for (int s = 0; s < KSEL; ++s) {
        unsigned k0 = (p0 < KSEL) ? bl[0 * KSEL + p0] : 0xFFFFFFFFu;
        unsigned k1 = (p1 < KSEL) ? bl[1 * KSEL + p1] : 0xFFFFFFFFu;
        unsigned k2 = (p2 < KSEL) ? bl[2 * KSEL + p2] : 0xFFFFFFFFu;
        unsigned k3 = (p3 < KSEL) ? bl[3 * KSEL + p3] : 0xFFFFFFFFu;
        unsigned bk = k0; int bs = 0;
        if (k1 < bk) { bk = k1; bs = 1; }
        if (k2 < bk) { bk = k2; bs = 2; }
        if (k3 < bk) { bk = k3; bs = 3; }
        pq[s] = bk;
        if (bs == 0) ++p0; else if (bs == 1) ++p1; else if (bs == 2) ++p2; else ++p3;
      }
    }
    __syncthreads();

    const float* qrow = P + ((size_t)r << 6);
    float4 q4[16];
#pragma unroll
    for (int t = 0; t < 16; ++t) q4[t] = ((const float4*)qrow)[t];
#pragma unroll 1
    for (int j = 0; j < 3; ++j) {
      int cand = st * 3 + j;
      unsigned key = pool[qi * KSEL + cand];
      int m = (int)(key & 0x7FFu);
      const float* prow = P + ((size_t)(b * NPTS + m) << 6);
      double a0 = 0.0, a1 = 0.0;
#pragma unroll
      for (int t = 0; t < 16; ++t) {
        float4 pv = ((const float4*)prow)[t];
        double d0 = (double)pv.x - (double)q4[t].x;
        double d1 = (double)pv.y - (double)q4[t].y;
        double d2 = (double)pv.z - (double)q4[t].z;
        double d3 = (double)pv.w - (double)q4[t].w;
        a0 = fma(d1, d1, fma(d0, d0, a0));
        a1 = fma(d3, d3, fma(d2, d2, a1));
      }
      cd[qi * KSEL + cand] = a0 + a1;
    }
    __syncthreads();

    int* op = IDX + (size_t)r * KNN;
#pragma unroll 1
    for (int j = 0; j < 3; ++j) {
      int cand = st * 3 + j;
      double dv = cd[qi * KSEL + cand];
      int iv = (int)(pool[qi * KSEL + cand] & 0x7FFu);
      int rk = 0;
#pragma unroll 1
      for (int t = 0; t < KSEL; ++t) {
        double dt = cd[qi * KSEL + t];
        int it = (int)(pool[qi * KSEL + t] & 0x7FFu);
        rk += ((dt < dv) || (dt == dv && it < iv)) ? 1 : 0;
      }
      if (rk < KNN) op[rk] = iv;
    }
  }
}

// ---------------------------------------------------------------------------
// K4: fused gather (bf16 U,V) + maxpool + BN-stat partials. Z stored bf16.
// ---------------------------------------------------------------------------
__global__ __launch_bounds__(256) void gstats_kernel(
    const unsigned short* __restrict__ Uh, const unsigned short* __restrict__ Vh,
    const int* __restrict__ IDX, unsigned short* __restrict__ Zh,
    float* __restrict__ STATS) {
  const int r0 = blockIdx.x * 16;
  const int tid = threadIdx.x;
  const int og = tid & 15, nl = tid >> 4;
  const int r = r0 + nl;
  const int b = r >> 11;
  const unsigned short* Vb = Vh + ((size_t)b << 11) * CO;

  __shared__ int ii[16 * KNN];
  __shared__ float red[4][5][128];

  for (int t = tid; t < 16 * KNN; t += 256) ii[t] = IDX[(size_t)r0 * KNN + t];
  __syncthreads();

  float vmax[8], svr[8], svvr[8];
#pragma unroll
  for (int j = 0; j < 8; ++j) { vmax[j] = -3.4e38f; svr[j] = 0.f; svvr[j] = 0.f; }
#pragma unroll 4
  for (int k = 0; k < KNN; ++k) {
    int idx = ii[nl * KNN + k];
    u16x8 hv = *(const u16x8*)(Vb + (size_t)idx * CO + og * 8);
#pragma unroll
    for (int j = 0; j < 8; ++j) {
      float v = bf2f((unsigned short)hv[j]);
      vmax[j] = fmaxf(vmax[j], v);
      svr[j] += v;
      svvr[j] = fmaf(v, v, svvr[j]);
    }
  }
  size_t ob = (size_t)r * CO + og * 8;
  u16x8 hu = *(const u16x8*)(Uh + ob);
  float uu[8];
#pragma unroll
  for (int j = 0; j < 8; ++j) uu[j] = bf2f((unsigned short)hu[j]);
  u16x8 zh;
#pragma unroll
  for (int j = 0; j < 8; ++j) zh[j] = f2bf_rne(uu[j] + vmax[j]);
  *(u16x8*)(Zh + ob) = zh;

  float pu[8], puu[8], psv[8], pusv[8], psvv[8];
#pragma unroll
  for (int j = 0; j < 8; ++j) {
    pu[j] = uu[j];
    puu[j] = uu[j] * uu[j];
    psv[j] = svr[j];
    pusv[j] = uu[j] * svr[j];
    psvv[j] = svvr[j];
  }
#pragma unroll
  for (int j = 0; j < 8; ++j) {
    pu[j]   += __shfl_xor(pu[j], 16);   pu[j]   += __shfl_xor(pu[j], 32);
    puu[j]  += __shfl_xor(puu[j], 16);  puu[j]  += __shfl_xor(puu[j], 32);
    psv[j]  += __shfl_xor(psv[j], 16);  psv[j]  += __shfl_xor(psv[j], 32);
    pusv[j] += __shfl_xor(pusv[j], 16); pusv[j] += __shfl_xor(pusv[j], 32);
    psvv[j] += __shfl_xor(psvv[j], 16); psvv[j] += __shfl_xor(psvv[j], 32);
  }
  const int w = tid >> 6;
  if ((tid & 0x30) == 0) {
#pragma unroll
    for (int j = 0; j < 8; ++j) {
      int c = og * 8 + j;
      red[w][0][c] = pu[j];  red[w][1][c] = puu[j];  red[w][2][c] = psv[j];
      red[w][3][c] = pusv[j]; red[w][4][c] = psvv[j];
    }
  }
  __syncthreads();
  if (tid < 128) {
#pragma unroll
    for (int s = 0; s < 5; ++s) {
      float v4 = red[0][s][tid] + red[1][s][tid] + red[2][s][tid] + red[3][s][tid];
      atomicAdd(&STATS[s * CO + tid], v4);
    }
  }
}

// ---------------------------------------------------------------------------
// K5: affine + ReLU + transpose write (bf16 Z in), per-block BN finalize.
// ---------------------------------------------------------------------------
__global__ __launch_bounds__(256) void out_kernel(
    const unsigned short* __restrict__ Zh, const float* __restrict__ STATS,
    const float* __restrict__ bias, const float* __restrict__ gamma,
    const float* __restrict__ beta, float* __restrict__ out) {
  const int n0 = blockIdx.x * 64, o0 = blockIdx.y * 32, b = blockIdx.z;
  const int tid = threadIdx.x;
  __shared__ float tile[64 * 33];
  __shared__ float fs[32], ft[32];
  if (tid < 32) {
    const int o = o0 + tid;
    const float M = (float)(BATCH * NPTS * KNN);
    const float Kf = (float)KNN;
    float su = STATS[0 * CO + o], suu = STATS[1 * CO + o], ssv = STATS[2 * CO + o];
    float susv = STATS[3 * CO + o], ssvv = STATS[4 * CO + o];
    float bo = bias[o];
    float lin = (Kf * su + ssv) / M;
    float mean = lin + bo;
    float ey2 = (Kf * suu + ssvv + 2.0f * susv) / M + 2.0f * bo * lin + bo * bo;
    float var = ey2 - mean * mean;
    float scale = gamma[o] * rsqrtf(var + 1e-5f);
    fs[tid] = scale;
    ft[tid] = (bo - mean) * scale + beta[o];
  }
#pragma unroll
  for (int j = 0; j < 8; ++j) {
    int e = j * 256 + tid;
    int ol = e & 31, nl = e >> 5;
    tile[nl * 33 + ol] = bf2f(Zh[(size_t)(b * NPTS + n0 + nl) * CO + o0 + ol]);
  }
  __syncthreads();
#pragma unroll
  for (int j = 0; j < 8; ++j) {
    int e = j * 256 + tid;
    int nl = e & 63, ol = e >> 6;
    float v = fmaf(tile[nl * 33 + ol], fs[ol], ft[ol]);
    out[(size_t)(b * CO + o0 + ol) * NPTS + n0 + nl] = fmaxf(v, 0.0f);
  }
}

// ---------------------------------------------------------------------------
extern "C" void kernel_launch(void* const* d_in, const int* in_sizes, int n_in,
                              void* d_out, int out_size, void* d_ws, size_t ws_size,
                              hipStream_t stream) {
  const float* x = (const float*)d_in[0];
  const float* W = (const float*)d_in[1];
  const float* bias = (const float*)d_in[2];
  const float* gamma = (const float*)d_in[3];
  const float* beta = (const float*)d_in[4];
  float* out = (float*)d_out;
  float* ws = (float*)d_ws;

  const size_t NR = (size_t)BATCH * NPTS;  // 16384
  size_t off = 0;
  float* P = ws + off;                      off += NR * CIN;
  unsigned short* PG = (unsigned short*)(ws + off); off += NR * CIN;
  float* SQ = ws + off;                     off += NR;
  int* IDX = (int*)(ws + off);              off += NR * KNN;
  unsigned short* Uh = (unsigned short*)(ws + off); off += NR * CO / 2;
  unsigned short* Vh = (unsigned short*)(ws + off); off += NR * CO / 2;
  unsigned* POOLS = (unsigned*)(ws + off);  off += NR * NSPLIT * KSEL;
  float* STATS = ws + off;                  off += 5 * CO;
  // Zh (bf16, 4 MB) aliases P (dead after merge_proj).
  unsigned short* Zh = (unsigned short*)ws;
  if (ws_size < off * sizeof(float)) return;

  prep_kernel<<<dim3(NPTS / 32, BATCH), 256, 0, stream>>>(x, P, PG, SQ, STATS);
  knn_part_kernel<<<dim3(NPTS / 64, NSPLIT, BATCH), 256, 0, stream>>>(PG, SQ, POOLS);
  merge_proj_kernel<<<dim3(512 + NR / 32), 256, 0, stream>>>(P, W, POOLS, IDX, Uh, Vh);
  gstats_kernel<<<dim3(NR / 16), 256, 0, stream>>>(Uh, Vh, IDX, Zh, STATS);
  out_kernel<<<dim3(NPTS / 64, CO / 32, BATCH), 256, 0, stream>>>(Zh, STATS, bias, gamma, beta, out);
}